// Round 12
// baseline (142.121 us; speedup 1.0000x reference)
//
#include <hip/hip_runtime.h>
#include <hip/hip_bf16.h>
#include <stdint.h>
#include <math.h>

#define NHEAD 16
#define DK 64
#define SEQ 2048
#define BATCH 2
#define DMODEL 1024

typedef __attribute__((ext_vector_type(8))) short short8_t;
typedef __attribute__((ext_vector_type(4))) short short4_t;
typedef __attribute__((ext_vector_type(4))) float f32x4;

#define MFMA(a, b, c) __builtin_amdgcn_mfma_f32_16x16x32_bf16(a, b, c, 0, 0, 0)
#define MFMA16(a, b, c) __builtin_amdgcn_mfma_f32_16x16x16bf16_1k(a, b, c, 0, 0, 0)

__device__ __forceinline__ unsigned short f2bf(float f) {
    union { __hip_bfloat16 b; unsigned short u; } c;
    c.b = __float2bfloat16(f);
    return c.u;
}

// ---------------------------------------------------------------------------
// bucket_kernel: per (bh, which) stable-partition indices by hash value.
// order[pos] = original idx; inv[idx] = pos; cnts[which*32+bh] = #zeros.
// ---------------------------------------------------------------------------
__global__ __launch_bounds__(256) void bucket_kernel(
    const int* __restrict__ hq, const int* __restrict__ hk,
    int* __restrict__ qorder, int* __restrict__ korder,
    int* __restrict__ qinv, int* __restrict__ kinv, int* __restrict__ cnts)
{
    const int blk = blockIdx.x;          // 0..63
    const int bh = blk >> 1;
    const int which = blk & 1;
    const int* src = (which ? hk : hq) + (size_t)bh * SEQ;
    int* dst = (which ? korder : qorder) + (size_t)bh * SEQ;
    int* ivd = (which ? kinv : qinv) + (size_t)bh * SEQ;

    __shared__ int cnt[257];
    const int t = threadIdx.x;           // 0..255
    int h[8]; int c = 0;
#pragma unroll
    for (int j = 0; j < 8; j++) { h[j] = src[t * 8 + j]; c += (h[j] == 0); }
    cnt[t] = c;
    __syncthreads();
    if (t == 0) {
        int run = 0;
        for (int i = 0; i < 256; i++) { int v = cnt[i]; cnt[i] = run; run += v; }
        cnt[256] = run;
    }
    __syncthreads();
    const int nz = cnt[256];
    int zpos = cnt[t];
    int opos = nz + t * 8 - cnt[t];
#pragma unroll
    for (int j = 0; j < 8; j++) {
        int idx = t * 8 + j;
        if (h[j] == 0) { dst[zpos] = idx; ivd[idx] = zpos; zpos++; }
        else           { dst[opos] = idx; ivd[idx] = opos; opos++; }
    }
    if (t == 0) cnts[which * 32 + bh] = nz;
}

// ---------------------------------------------------------------------------
// cvt_w: Wq, Wk, Wv (1M f32 each) -> bf16 in one launch.
// ---------------------------------------------------------------------------
__global__ __launch_bounds__(256) void cvt_w_kernel(
    const float* __restrict__ W0, const float* __restrict__ W1,
    const float* __restrict__ W2,
    unsigned short* __restrict__ o0, unsigned short* __restrict__ o1,
    unsigned short* __restrict__ o2)
{
    const size_t t = (size_t)blockIdx.x * 256 + threadIdx.x;   // 0..393215
    const float* s; unsigned short* d; size_t i8;
    if (t < 131072)      { s = W0; d = o0; i8 = t * 8; }
    else if (t < 262144) { s = W1; d = o1; i8 = (t - 131072) * 8; }
    else                 { s = W2; d = o2; i8 = (t - 262144) * 8; }
    f32x4 v0 = *(const f32x4*)(s + i8);
    f32x4 v1 = *(const f32x4*)(s + i8 + 4);
    union { short8_t v; unsigned short u[8]; } o;
#pragma unroll
    for (int j = 0; j < 4; j++) {
        o.u[j]     = f2bf(v0[j]);
        o.u[4 + j] = f2bf(v1[j]);
    }
    *(short8_t*)(d + i8) = o.v;
}

// ---------------------------------------------------------------------------
// proj_nat: natural-order GEMM, tile 128(A) x 64(B), BK=64, double-buffered.
// X is read as **f32 directly** (reg-staged: global->reg, cvt, ds_write);
// W is bf16 (pre-converted) staged via global_load_lds. Grid 512, XCD-grouped
// on flat&7 -> per-XCD L2 set = 2MB W-bf16 + 2MB X-f32 chunk.
// MODE 0: A=X(f32), B=W. C[gm][od]; row-scatter via inv -> dst[bh][pos][d].
// MODE 1: A=W, B=X(f32). C[od][gm]; col-scatter via inv -> dst[bh][d][pos].
// ---------------------------------------------------------------------------
template <int MODE>
__global__ __launch_bounds__(256, 3) void proj_nat(
    const float* __restrict__ Xf,            // [4096][1024] f32
    const unsigned short* __restrict__ Wb,   // [1024][1024] bf16
    const float* __restrict__ bias,
    const int* __restrict__ inv,             // [32][2048]
    unsigned short* __restrict__ dst)
{
    __shared__ unsigned short At[2][128 * 64];
    __shared__ unsigned short Bt[2][64 * 64];

    const int tid = threadIdx.x;
    const int lane = tid & 63;
    const int wv = tid >> 6;
    const int fr = lane & 15;
    const int fg = lane >> 4;
    const int srw = lane >> 3;
    const int su = lane & 7;

    const int flat = blockIdx.x;            // 0..511
    const int xg = flat & 7;                // XCD group (round-robin dispatch)
    const int j = flat >> 3;                // 0..63

    int m0, n0;
    if constexpr (MODE == 0) { m0 = ((xg << 2) + (j >> 4)) * 128; n0 = (j & 15) * 64; }
    else                     { m0 = (j & 7) * 128; n0 = ((xg << 3) + (j >> 3)) * 64; }

    // X: reg-staged f32. XI groups of 8 rows per wave.
    constexpr int XI = (MODE == 0) ? 4 : 2;     // X tile rows: 128 (A) or 64 (B)
    constexpr int WI = (MODE == 0) ? 2 : 4;     // W tile rows: 64 (B) or 128 (A)
    const int xBaseG = (MODE == 0) ? m0 : n0;   // X global row base
    const int wBaseG = (MODE == 0) ? n0 : m0;   // W global row base

#define XDST(BI) ((MODE == 0) ? At[BI] : Bt[BI])
#define WDST(BI) ((MODE == 0) ? Bt[BI] : At[BI])

    const float* xSrc[XI]; int xOff[XI];
#pragma unroll
    for (int i = 0; i < XI; i++) {
        int lr = wv * (XI * 8) + i * 8 + srw;   // local row in X tile
        xSrc[i] = Xf + (size_t)(xBaseG + lr) * DMODEL + su * 8;
        xOff[i] = lr * 64 + ((su ^ (lr & 7)) << 3);
    }
    const unsigned short* wSrc[WI]; int wBase[WI];
#pragma unroll
    for (int i = 0; i < WI; i++) {
        int lr0 = wv * (WI * 8) + i * 8;
        int lr = lr0 + srw;
        wSrc[i] = Wb + (size_t)(wBaseG + lr) * DMODEL + ((su ^ (lr & 7)) << 3);
        wBase[i] = lr0 * 64;                    // wave-uniform LDS base
    }

    f32x4 Lo[XI][2];

#define XLOAD(K0)                                                             \
    {                                                                         \
        _Pragma("unroll")                                                     \
        for (int i = 0; i < XI; i++) {                                        \
            Lo[i][0] = *(const f32x4*)(xSrc[i] + (K0));                       \
            Lo[i][1] = *(const f32x4*)(xSrc[i] + (K0) + 4);                   \
        }                                                                     \
    }
#define XWRITE(BI)                                                            \
    {                                                                         \
        _Pragma("unroll")                                                     \
        for (int i = 0; i < XI; i++) {                                        \
            union { short8_t v; unsigned short u[8]; } o;                     \
            _Pragma("unroll")                                                 \
            for (int q = 0; q < 4; q++) {                                     \
                o.u[q]     = f2bf(Lo[i][0][q]);                               \
                o.u[4 + q] = f2bf(Lo[i][1][q]);                               \
            }                                                                 \
            *(short8_t*)&XDST(BI)[xOff[i]] = o.v;                             \
        }                                                                     \
    }
#define WSTAGE(K0, BI)                                                        \
    {                                                                         \
        _Pragma("unroll")                                                     \
        for (int i = 0; i < WI; i++)                                          \
            __builtin_amdgcn_global_load_lds(                                 \
                (const void*)(wSrc[i] + (K0)),                                \
                (void*)&WDST(BI)[wBase[i]], 16, 0, 0);                        \
    }

    f32x4 acc[2][4];
    const f32x4 fzero = {0.f, 0.f, 0.f, 0.f};
#pragma unroll
    for (int mf = 0; mf < 2; mf++)
#pragma unroll
        for (int nf = 0; nf < 4; nf++) acc[mf][nf] = fzero;

    XLOAD(0); WSTAGE(0, 0); XWRITE(0);
    __syncthreads();
    int cur = 0;

    for (int kk = 0; kk < 16; kk++) {
        if (kk < 15) {
            XLOAD((kk + 1) * 64);            // f32 loads in flight under compute
            WSTAGE((kk + 1) * 64, cur ^ 1);  // async W stage to other buffer
        }

        short8_t a[2][2], b[4][2];
#pragma unroll
        for (int mf = 0; mf < 2; mf++)
#pragma unroll
            for (int ks = 0; ks < 2; ks++) {
                int r = wv * 32 + mf * 16 + fr;
                int u = (ks * 4 + fg) ^ (fr & 7);
                a[mf][ks] = *(const short8_t*)&At[cur][r * 64 + u * 8];
            }
#pragma unroll
        for (int nf = 0; nf < 4; nf++)
#pragma unroll
            for (int ks = 0; ks < 2; ks++) {
                int r = nf * 16 + fr;
                int u = (ks * 4 + fg) ^ (fr & 7);
                b[nf][ks] = *(const short8_t*)&Bt[cur][r * 64 + u * 8];
            }
#pragma unroll
        for (int ks = 0; ks < 2; ks++)
#pragma unroll
            for (int mf = 0; mf < 2; mf++)
#pragma unroll
                for (int nf = 0; nf < 4; nf++)
                    acc[mf][nf] = MFMA(a[mf][ks], b[nf][ks], acc[mf][nf]);

        if (kk < 15) XWRITE(cur ^ 1);        // waits f32 loads, cvt, ds_write
        __syncthreads();                     // drains lgkm+vm; swaps buffers
        cur ^= 1;
    }
#undef XLOAD
#undef XWRITE
#undef WSTAGE
#undef XDST
#undef WDST

    if constexpr (MODE == 0) {
        const int hh = n0 >> 6;
#pragma unroll
        for (int mf = 0; mf < 2; mf++)
#pragma unroll
            for (int r = 0; r < 4; r++) {
                int gm = m0 + wv * 32 + mf * 16 + fg * 4 + r;   // b*2048+l
                int bb = gm >> 11;
                int bh = bb * NHEAD + hh;
                int pos = inv[(size_t)bh * SEQ + (gm & (SEQ - 1))];
                unsigned short* drow = dst + ((size_t)bh * SEQ + pos) * DK;
#pragma unroll
                for (int nf = 0; nf < 4; nf++) {
                    float v = acc[mf][nf][r] + bias[n0 + nf * 16 + fr];
                    drow[nf * 16 + fr] = f2bf(v);
                }
            }
    } else {
        const int bb = n0 >> 11;
#pragma unroll
        for (int mf = 0; mf < 2; mf++)
#pragma unroll
            for (int r = 0; r < 4; r++) {
                int od = m0 + wv * 32 + mf * 16 + fg * 4 + r;   // h*64+d
                int h = od >> 6;
                int bh = bb * NHEAD + h;
                float bv = bias[od];
                unsigned short* drow = dst + ((size_t)bh * DK + (od & 63)) * SEQ;
#pragma unroll
                for (int nf = 0; nf < 4; nf++) {
                    int gm = n0 + nf * 16 + fr;
                    int pos = inv[(size_t)bh * SEQ + (gm & (SEQ - 1))];
                    drow[pos] = f2bf(acc[mf][nf][r] + bv);      // sorted V^T
                }
            }
    }
}

// ---------------------------------------------------------------------------
// LSH flash attention: bucket-sorted, bucket-aligned q-slots, swapped QK^T,
// in-register PV (16x16x16), psum via MFMA, counted-vmcnt 2-phase staging.
// launch_bounds(256,4): 128-VGPR budget (4 blocks/CU; LDS cap is 5).
// ---------------------------------------------------------------------------
__global__ __launch_bounds__(256, 4) void lsh_attn_kernel(
    const unsigned short* __restrict__ Qs,
    const unsigned short* __restrict__ Ks, const unsigned short* __restrict__ Vst,
    const int* __restrict__ qorder, const int* __restrict__ cnts,
    float* __restrict__ out)
{
    __shared__ unsigned short KtL[2][64 * 64];
    __shared__ unsigned short VtL[2][64 * 64];

    const int tid = threadIdx.x;
    const int lane = tid & 63;
    const int wv = tid >> 6;
    const int fr = lane & 15;
    const int fg = lane >> 4;

    // XCD-grouped mapping: 1056 = 8 XCD x (4 heads x 33 slots)
    const int flat = blockIdx.x;
    const int xcd = flat & 7;
    const int s2 = flat >> 3;                 // 0..131
    const int bh = (xcd << 2) + (s2 / 33);    // b*16 + h
    const int slot = s2 % 33;

    const int nq0 = cnts[bh];
    const int nk0 = cnts[32 + bh];
    const int c0 = (nq0 + 63) >> 6;           // q-tiles covering bucket 0

    int B, qlo, qhi;
    if (slot < c0) {
        B = 0; qlo = slot << 6; qhi = min(qlo + 64, nq0);
    } else {
        B = 1; qlo = nq0 + ((slot - c0) << 6);
        if (qlo >= SEQ) return;               // block-uniform: safe w/ barriers
        qhi = min(qlo + 64, SEQ);
    }
    const int klo = B ? (nk0 >> 6) : 0;
    const int khi = B ? (SEQ >> 6) : ((nk0 + 63) >> 6);
    const int nt = khi - klo;

    const size_t base = (size_t)bh * SEQ * DK;
    const unsigned short* Kb = Ks + base;                    // [pos][d]
    const unsigned short* Vb = Vst + (size_t)bh * DK * SEQ;  // [d][pos]

    const int srw = lane >> 3;
    const int su = lane & 7;

    // Q fragments (B-operand of swapped QK: lane fr = q-row qlo + wv*16 + fr)
    short8_t q_hi[2];
    {
        const size_t ro = base + (size_t)(qlo + wv * 16 + fr) * DK;
        q_hi[0] = *(const short8_t*)(Qs + ro + fg * 8);
        q_hi[1] = *(const short8_t*)(Qs + ro + 32 + fg * 8);
    }

    const int swz = fr & 7;
    const int u0 = ((fg ^ swz) << 3);
    const int u1 = (((4 + fg) ^ swz) << 3);
    int vuoff[4];
#pragma unroll
    for (int kg = 0; kg < 4; kg++)
        vuoff[kg] = (((kg * 2 + (fg >> 1)) ^ swz) << 3) + ((fg & 1) << 2);

    const float C2 = 0.18033688011112042f;    // 0.125 * log2(e)
    const float B2 = -14.426950408889634f;    // -10 * log2(e)

    const short4_t ones = {(short)0x3F80, (short)0x3F80, (short)0x3F80, (short)0x3F80};
    f32x4 acc_sum;
    f32x4 o_acc[4];
    const f32x4 fzero = {0.f, 0.f, 0.f, 0.f};
    acc_sum = fzero;
#pragma unroll
    for (int t = 0; t < 4; t++) o_acc[t] = fzero;

#define STAGE(T, BI)                                                          \
    {                                                                         \
        const int k0s = (T) << 6;                                             \
        _Pragma("unroll")                                                     \
        for (int i = 0; i < 2; i++) {                                         \
            const int r = wv * 16 + i * 8 + srw;                              \
            const int uo = ((su ^ (r & 7)) << 3);                             \
            __builtin_amdgcn_global_load_lds(                                 \
                (const void*)(Kb + (size_t)(k0s + r) * DK + uo),              \
                (void*)&KtL[BI][(wv * 16 + i * 8) * 64], 16, 0, 0);           \
            __builtin_amdgcn_global_load_lds(                                 \
                (const void*)(Vb + (size_t)r * SEQ + k0s + uo),               \
                (void*)&VtL[BI][(wv * 16 + i * 8) * 64], 16, 0, 0);           \
        }                                                                     \
    }

    STAGE(klo, 0);
    int cur = 0;

    for (int i = 0; i < nt; i++) {
        if (i + 1 < nt) {
            STAGE(klo + i + 1, cur ^ 1);      // 4 more loads in flight
            asm volatile("s_waitcnt vmcnt(4)" ::: "memory");  // tile i landed
        } else {
            asm volatile("s_waitcnt vmcnt(0)" ::: "memory");
        }
        __builtin_amdgcn_sched_barrier(0);
        __builtin_amdgcn_s_barrier();         // tile i visible to all waves
        __builtin_amdgcn_sched_barrier(0);

        const int k0 = (klo + i) << 6;

        // ---- V fragments into regs early (independent of S) ----
        short4_t vfr[4][4];
#pragma unroll
        for (int dt = 0; dt < 4; dt++)
#pragma unroll
            for (int kg = 0; kg < 4; kg++)
                vfr[dt][kg] = *(const short4_t*)&VtL[cur][(dt * 16 + fr) * 64 + vuoff[kg]];

        // ---- S^T = K Q^T (8 MFMA; A = K rows, B = Q) ----
        f32x4 s[4];
#pragma unroll
        for (int kg = 0; kg < 4; kg++) {
            const int rr = (kg * 16 + fr) * 64;
            short8_t kc0 = *(const short8_t*)&KtL[cur][rr + u0];
            short8_t kc1 = *(const short8_t*)&KtL[cur][rr + u1];
            f32x4 a = fzero;
            a = MFMA(kc0, q_hi[0], a);
            a = MFMA(kc1, q_hi[1], a);
            s[kg] = a;
        }

        // ---- softmax: p = exp2(s*C2 + B2); boundary tile masks by position ----
        short4_t pk[4];
        const bool mixed = B ? (k0 < nk0) : (k0 + 64 > nk0);
        if (!mixed) {
#pragma unroll
            for (int kg = 0; kg < 4; kg++) {
                union { short4_t v; unsigned short u[4]; } P;
#pragma unroll
                for (int r = 0; r < 4; r++)
                    P.u[r] = f2bf(exp2f(fmaf(s[kg][r], C2, B2)));
                pk[kg] = P.v;
            }
        } else {
#pragma unroll
            for (int kg = 0; kg < 4; kg++) {
                union { short4_t v; unsigned short u[4]; } P;
#pragma unroll
                for (int r = 0; r < 4; r++) {
                    int cb = (k0 + kg * 16 + fg * 4 + r) >= nk0;
                    float basev = (cb == B) ? B2 : -1e9f;
                    P.u[r] = f2bf(exp2f(fmaf(s[kg][r], C2, basev)));
                }
                pk[kg] = P.v;
            }
        }

        // ---- psum via MFMA: acc_sum[.][q] += sum_k P^T[k][q] ----
#pragma unroll
        for (int kg = 0; kg < 4; kg++)
            acc_sum = MFMA16(ones, pk[kg], acc_sum);

        // ---- O^T += V^T P^T (in-register A and B) ----
#pragma unroll
        for (int dt = 0; dt < 4; dt++) {
            f32x4 acc = o_acc[dt];
#pragma unroll
            for (int kg = 0; kg < 4; kg++)
                acc = MFMA16(vfr[dt][kg], pk[kg], acc);
            o_acc[dt] = acc;
        }

        __builtin_amdgcn_sched_barrier(0);
        __builtin_amdgcn_s_barrier();         // buf[cur] fully consumed
        __builtin_amdgcn_sched_barrier(0);
        cur ^= 1;
    }
#undef STAGE

    // acc_sum rows are identical; element 0 already holds the full psum for q=fr
    const float psum = acc_sum[0];

    // ---- epilogue: row q=fr scatter via qorder; cols contiguous -> float4 ----
    const int b = bh >> 4, h = bh & 15;
    const int qpos = qlo + wv * 16 + fr;
    if (qpos < qhi) {
        const int origq = qorder[(size_t)bh * SEQ + qpos];
        const float inv = 1.0f / psum;
        float* orow = out + ((size_t)(b * SEQ + origq)) * DMODEL + h * DK + fg * 4;
#pragma unroll
        for (int dt = 0; dt < 4; dt++) {
            f32x4 v = o_acc[dt];
            v *= inv;
            *(f32x4*)(orow + dt * 16) = v;
        }
    }
}

// ---------------------------------------------------------------------------

extern "C" void kernel_launch(void* const* d_in, const int* in_sizes, int n_in,
                              void* d_out, int out_size, void* d_ws, size_t ws_size,
                              hipStream_t stream)
{
    const float* query = (const float*)d_in[0];
    const float* key   = (const float*)d_in[1];
    const float* value = (const float*)d_in[2];
    const int* hash_q  = (const int*)d_in[3];
    const int* hash_k  = (const int*)d_in[4];
    const float* Wq    = (const float*)d_in[5];
    const float* bq    = (const float*)d_in[6];
    const float* Wk    = (const float*)d_in[7];
    const float* bk    = (const float*)d_in[8];
    const float* Wv    = (const float*)d_in[9];
    const float* bv    = (const float*)d_in[10];
    float* out = (float*)d_out;

    const size_t plane = (size_t)BATCH * NHEAD * SEQ * DK;   // 4,194,304 elems
    const size_t wsz = (size_t)DMODEL * DMODEL;              // 1,048,576 elems
    unsigned short* ws = (unsigned short*)d_ws;
    unsigned short* pQ  = ws;
    unsigned short* pK  = ws + plane;
    unsigned short* pVt = ws + 2 * plane;                     // sorted V^T
    unsigned short* wqb = ws + 3 * plane;
    unsigned short* wkb = wqb + wsz;
    unsigned short* wvb = wkb + wsz;
    int* ip = (int*)(wvb + wsz);
    int* qorder = ip;                 // 32*2048
    int* korder = ip + 65536;
    int* qinv   = ip + 131072;
    int* kinv   = ip + 196608;
    int* cnts   = ip + 262144;        // 64

    bucket_kernel<<<64, 256, 0, stream>>>(hash_q, hash_k, qorder, korder,
                                          qinv, kinv, cnts);

    cvt_w_kernel<<<1536, 256, 0, stream>>>(Wq, Wk, Wv, wqb, wkb, wvb);

    proj_nat<0><<<512, 256, 0, stream>>>(query, wqb, bq, qinv, pQ);
    proj_nat<0><<<512, 256, 0, stream>>>(key,   wkb, bk, kinv, pK);
    proj_nat<1><<<512, 256, 0, stream>>>(value, wvb, bv, kinv, pVt);

    lsh_attn_kernel<<<dim3(1056), 256, 0, stream>>>(pQ, pK, pVt,
                                                    qorder, cnts, out);
}

// Round 13
// 135.093 us; speedup vs baseline: 1.0520x; 1.0520x over previous
//
#include <hip/hip_runtime.h>
#include <hip/hip_bf16.h>
#include <stdint.h>
#include <math.h>

#define NHEAD 16
#define DK 64
#define SEQ 2048
#define BATCH 2
#define DMODEL 1024

typedef __attribute__((ext_vector_type(8))) short short8_t;
typedef __attribute__((ext_vector_type(4))) short short4_t;
typedef __attribute__((ext_vector_type(4))) float f32x4;

#define MFMA(a, b, c) __builtin_amdgcn_mfma_f32_16x16x32_bf16(a, b, c, 0, 0, 0)
#define MFMA16(a, b, c) __builtin_amdgcn_mfma_f32_16x16x16bf16_1k(a, b, c, 0, 0, 0)

__device__ __forceinline__ unsigned short f2bf(float f) {
    union { __hip_bfloat16 b; unsigned short u; } c;
    c.b = __float2bfloat16(f);
    return c.u;
}

// ---------------------------------------------------------------------------
// bucket_kernel: per (bh, which) stable-partition indices by hash value.
// ---------------------------------------------------------------------------
__global__ __launch_bounds__(256) void bucket_kernel(
    const int* __restrict__ hq, const int* __restrict__ hk,
    int* __restrict__ qorder, int* __restrict__ korder,
    int* __restrict__ qinv, int* __restrict__ kinv, int* __restrict__ cnts)
{
    const int blk = blockIdx.x;          // 0..63
    const int bh = blk >> 1;
    const int which = blk & 1;
    const int* src = (which ? hk : hq) + (size_t)bh * SEQ;
    int* dst = (which ? korder : qorder) + (size_t)bh * SEQ;
    int* ivd = (which ? kinv : qinv) + (size_t)bh * SEQ;

    __shared__ int cnt[257];
    const int t = threadIdx.x;           // 0..255
    int h[8]; int c = 0;
#pragma unroll
    for (int j = 0; j < 8; j++) { h[j] = src[t * 8 + j]; c += (h[j] == 0); }
    cnt[t] = c;
    __syncthreads();
    if (t == 0) {
        int run = 0;
        for (int i = 0; i < 256; i++) { int v = cnt[i]; cnt[i] = run; run += v; }
        cnt[256] = run;
    }
    __syncthreads();
    const int nz = cnt[256];
    int zpos = cnt[t];
    int opos = nz + t * 8 - cnt[t];
#pragma unroll
    for (int j = 0; j < 8; j++) {
        int idx = t * 8 + j;
        if (h[j] == 0) { dst[zpos] = idx; ivd[idx] = zpos; zpos++; }
        else           { dst[opos] = idx; ivd[idx] = opos; opos++; }
    }
    if (t == 0) cnts[which * 32 + bh] = nz;
}

// ---------------------------------------------------------------------------
// cvt_xw: X (4M f32) -> bf16, W (1M f32) -> bf16.
// ---------------------------------------------------------------------------
__global__ __launch_bounds__(256) void cvt_xw_kernel(
    const float* __restrict__ X, const float* __restrict__ W,
    unsigned short* __restrict__ Xb, unsigned short* __restrict__ Wb)
{
    const size_t t = (size_t)blockIdx.x * 256 + threadIdx.x;
    const float* src;
    unsigned short* dst;
    size_t i8;
    if (t < 524288) { src = X; dst = Xb; i8 = t * 8; }
    else            { src = W; dst = Wb; i8 = (t - 524288) * 8; }
    f32x4 v0 = *(const f32x4*)(src + i8);
    f32x4 v1 = *(const f32x4*)(src + i8 + 4);
    union { short8_t v; unsigned short u[8]; } o;
#pragma unroll
    for (int j = 0; j < 4; j++) {
        o.u[j]     = f2bf(v0[j]);
        o.u[4 + j] = f2bf(v1[j]);
    }
    *(short8_t*)(dst + i8) = o.v;
}

// ---------------------------------------------------------------------------
// proj_nat (r11-proven): natural-order GEMM, tile 128(A) x 64(B), BK=64,
// double-buffered global_load_lds with counted vmcnt. Grid 512, XCD-grouped.
// MODE 0: A=X, B=W. C[gm][od]; row-scatter via inv -> dst[bh][pos][d] (Q/K).
// MODE 1: A=W, B=X. C[od][gm]; natural store -> dst[bh][d][gm] (V^T natural).
// ---------------------------------------------------------------------------
template <int MODE>
__global__ __launch_bounds__(256) void proj_nat(
    const unsigned short* __restrict__ Xb,   // [4096][1024]
    const unsigned short* __restrict__ Wb,   // [1024][1024]
    const float* __restrict__ bias,
    const int* __restrict__ inv,             // [32][2048] (MODE 0)
    unsigned short* __restrict__ dst)
{
    __shared__ unsigned short At[2][128 * 64];
    __shared__ unsigned short Bt[2][64 * 64];

    const int tid = threadIdx.x;
    const int lane = tid & 63;
    const int wv = tid >> 6;
    const int fr = lane & 15;
    const int fg = lane >> 4;
    const int srw = lane >> 3;
    const int su = lane & 7;

    const int flat = blockIdx.x;            // 0..511
    const int xg = flat & 7;                // XCD group (round-robin dispatch)
    const int j = flat >> 3;                // 0..63

    const unsigned short* Ap; const unsigned short* Bp;
    int m0, n0;
    if constexpr (MODE == 0) {
        Ap = Xb; Bp = Wb;
        m0 = ((xg << 2) + (j >> 4)) * 128;
        n0 = (j & 15) * 64;
    } else {
        Ap = Wb; Bp = Xb;
        m0 = (j & 7) * 128;
        n0 = ((xg << 3) + (j >> 3)) * 64;
    }

    const unsigned short* aS[4]; const unsigned short* bS[2];
#pragma unroll
    for (int i = 0; i < 4; i++) {
        int r = wv * 32 + i * 8 + srw;
        aS[i] = Ap + (size_t)(m0 + r) * DMODEL + ((su ^ (r & 7)) << 3);
    }
#pragma unroll
    for (int i = 0; i < 2; i++) {
        int r = wv * 16 + i * 8 + srw;
        bS[i] = Bp + (size_t)(n0 + r) * DMODEL + ((su ^ (r & 7)) << 3);
    }

    f32x4 acc[2][4];
    const f32x4 fzero = {0.f, 0.f, 0.f, 0.f};
#pragma unroll
    for (int mf = 0; mf < 2; mf++)
#pragma unroll
        for (int nf = 0; nf < 4; nf++) acc[mf][nf] = fzero;

#define PSTAGE(K0, BI)                                                        \
    {                                                                         \
        _Pragma("unroll")                                                     \
        for (int i = 0; i < 4; i++)                                           \
            __builtin_amdgcn_global_load_lds(                                 \
                (const void*)(aS[i] + (K0)),                                  \
                (void*)&At[BI][(wv * 32 + i * 8) * 64], 16, 0, 0);            \
        _Pragma("unroll")                                                     \
        for (int i = 0; i < 2; i++)                                           \
            __builtin_amdgcn_global_load_lds(                                 \
                (const void*)(bS[i] + (K0)),                                  \
                (void*)&Bt[BI][(wv * 16 + i * 8) * 64], 16, 0, 0);            \
    }

    PSTAGE(0, 0);
    int cur = 0;

    for (int kk = 0; kk < 16; kk++) {
        if (kk < 15) {
            PSTAGE((kk + 1) * 64, cur ^ 1);
            asm volatile("s_waitcnt vmcnt(6)" ::: "memory");  // tile kk landed
        } else {
            asm volatile("s_waitcnt vmcnt(0)" ::: "memory");
        }
        __builtin_amdgcn_sched_barrier(0);
        __builtin_amdgcn_s_barrier();
        __builtin_amdgcn_sched_barrier(0);

        short8_t a[2][2], b[4][2];
#pragma unroll
        for (int mf = 0; mf < 2; mf++)
#pragma unroll
            for (int ks = 0; ks < 2; ks++) {
                int r = wv * 32 + mf * 16 + fr;
                int u = (ks * 4 + fg) ^ (fr & 7);
                a[mf][ks] = *(const short8_t*)&At[cur][r * 64 + u * 8];
            }
#pragma unroll
        for (int nf = 0; nf < 4; nf++)
#pragma unroll
            for (int ks = 0; ks < 2; ks++) {
                int r = nf * 16 + fr;
                int u = (ks * 4 + fg) ^ (fr & 7);
                b[nf][ks] = *(const short8_t*)&Bt[cur][r * 64 + u * 8];
            }
#pragma unroll
        for (int ks = 0; ks < 2; ks++)
#pragma unroll
            for (int mf = 0; mf < 2; mf++)
#pragma unroll
                for (int nf = 0; nf < 4; nf++)
                    acc[mf][nf] = MFMA(a[mf][ks], b[nf][ks], acc[mf][nf]);

        __builtin_amdgcn_sched_barrier(0);
        __builtin_amdgcn_s_barrier();      // all reads of buf[cur] done
        __builtin_amdgcn_sched_barrier(0);
        cur ^= 1;
    }
#undef PSTAGE

    if constexpr (MODE == 0) {
        const int hh = n0 >> 6;
#pragma unroll
        for (int mf = 0; mf < 2; mf++)
#pragma unroll
            for (int r = 0; r < 4; r++) {
                int gm = m0 + wv * 32 + mf * 16 + fg * 4 + r;   // b*2048+l
                int bb = gm >> 11;
                int bh = bb * NHEAD + hh;
                int pos = inv[(size_t)bh * SEQ + (gm & (SEQ - 1))];
                unsigned short* drow = dst + ((size_t)bh * SEQ + pos) * DK;
#pragma unroll
                for (int nf = 0; nf < 4; nf++) {
                    float v = acc[mf][nf][r] + bias[n0 + nf * 16 + fr];
                    drow[nf * 16 + fr] = f2bf(v);
                }
            }
    } else {
        const int bb = n0 >> 11;
#pragma unroll
        for (int mf = 0; mf < 2; mf++)
#pragma unroll
            for (int r = 0; r < 4; r++) {
                int od = m0 + wv * 32 + mf * 16 + fg * 4 + r;   // h*64+d
                int h = od >> 6;
                int bh = bb * NHEAD + h;
                float bv = bias[od];
                unsigned short* drow =
                    dst + ((size_t)bh * DK + (od & 63)) * SEQ + (n0 & (SEQ - 1));
#pragma unroll
                for (int nf = 0; nf < 4; nf++) {
                    float v = acc[mf][nf][r] + bv;
                    drow[nf * 16 + fr] = f2bf(v);
                }
            }
    }
}

// ---------------------------------------------------------------------------
// vperm: Vs[bh][d][pos] = Vn[bh][d][korder[bh][pos]]  (gather along keys)
// ---------------------------------------------------------------------------
__global__ __launch_bounds__(256) void vperm_kernel(
    const unsigned short* __restrict__ Vn, const int* __restrict__ korder,
    unsigned short* __restrict__ Vs)
{
    const int blk = blockIdx.x;       // 0..2047 = bh*64 + d
    const int bh = blk >> 6;
    const int d  = blk & 63;
    const int t = threadIdx.x;        // pos = t*8
    const int* kop = korder + (size_t)bh * SEQ + t * 8;
    const unsigned short* src = Vn + ((size_t)bh * DK + d) * SEQ;
    union { short8_t v; unsigned short u[8]; } o;
#pragma unroll
    for (int j = 0; j < 8; j++) o.u[j] = src[kop[j]];
    *(short8_t*)(Vs + ((size_t)bh * DK + d) * SEQ + t * 8) = o.v;
}

// ---------------------------------------------------------------------------
// LSH flash attention, q-tile-fused: 128 q-rows per block (2 groups of 64),
// both processed against each staged 64-key tile -> staging/barriers per
// unit compute halve. Bucket-sorted, bucket-aligned 128-row q-slots,
// swapped QK^T, in-register PV, psum via MFMA, counted-vmcnt 2-phase.
// Grid: 32 heads x 17 slots = 544, XCD-grouped.
// ---------------------------------------------------------------------------
__global__ __launch_bounds__(256, 3) void lsh_attn_kernel(
    const unsigned short* __restrict__ Qs,
    const unsigned short* __restrict__ Ks, const unsigned short* __restrict__ Vst,
    const int* __restrict__ qorder, const int* __restrict__ cnts,
    float* __restrict__ out)
{
    __shared__ unsigned short KtL[2][64 * 64];
    __shared__ unsigned short VtL[2][64 * 64];

    const int tid = threadIdx.x;
    const int lane = tid & 63;
    const int wv = tid >> 6;
    const int fr = lane & 15;
    const int fg = lane >> 4;

    // XCD-grouped mapping: 544 = 8 XCD x (4 heads x 17 slots)
    const int flat = blockIdx.x;
    const int xcd = flat & 7;
    const int s2 = flat >> 3;                 // 0..67
    const int bh = (xcd << 2) + (s2 / 17);    // b*16 + h
    const int slot = s2 % 17;

    const int nq0 = cnts[bh];
    const int nk0 = cnts[32 + bh];
    const int c0 = (nq0 + 127) >> 7;          // 128-row q-slots covering bucket 0

    int B, qlo, qhi;
    if (slot < c0) {
        B = 0; qlo = slot << 7; qhi = min(qlo + 128, nq0);
    } else {
        B = 1; qlo = nq0 + ((slot - c0) << 7);
        if (qlo >= SEQ) return;               // block-uniform: safe w/ barriers
        qhi = min(qlo + 128, SEQ);
    }
    const int klo = B ? (nk0 >> 6) : 0;
    const int khi = B ? (SEQ >> 6) : ((nk0 + 63) >> 6);
    const int nt = khi - klo;

    const size_t base = (size_t)bh * SEQ * DK;
    const unsigned short* Kb = Ks + base;                    // [pos][d]
    const unsigned short* Vb = Vst + (size_t)bh * DK * SEQ;  // [d][pos]

    const int srw = lane >> 3;
    const int su = lane & 7;

    // Q fragments, two groups (rows qlo + g*64 + wv*16 + fr, clamped)
    short8_t q_hi[2][2];
#pragma unroll
    for (int g = 0; g < 2; g++) {
        int row = qlo + g * 64 + wv * 16 + fr;
        row = min(row, SEQ - 1);              // overshoot rows never stored
        const size_t ro = base + (size_t)row * DK;
        q_hi[g][0] = *(const short8_t*)(Qs + ro + fg * 8);
        q_hi[g][1] = *(const short8_t*)(Qs + ro + 32 + fg * 8);
    }

    const int swz = fr & 7;
    const int u0 = ((fg ^ swz) << 3);
    const int u1 = (((4 + fg) ^ swz) << 3);
    int vuoff[4];
#pragma unroll
    for (int kg = 0; kg < 4; kg++)
        vuoff[kg] = (((kg * 2 + (fg >> 1)) ^ swz) << 3) + ((fg & 1) << 2);

    const float C2 = 0.18033688011112042f;    // 0.125 * log2(e)
    const float B2 = -14.426950408889634f;    // -10 * log2(e)

    const short4_t ones = {(short)0x3F80, (short)0x3F80, (short)0x3F80, (short)0x3F80};
    f32x4 acc_sum[2];
    f32x4 o_acc[2][4];
    const f32x4 fzero = {0.f, 0.f, 0.f, 0.f};
#pragma unroll
    for (int g = 0; g < 2; g++) {
        acc_sum[g] = fzero;
#pragma unroll
        for (int t = 0; t < 4; t++) o_acc[g][t] = fzero;
    }

#define STAGE(T, BI)                                                          \
    {                                                                         \
        const int k0s = (T) << 6;                                             \
        _Pragma("unroll")                                                     \
        for (int i = 0; i < 2; i++) {                                         \
            const int r = wv * 16 + i * 8 + srw;                              \
            const int uo = ((su ^ (r & 7)) << 3);                             \
            __builtin_amdgcn_global_load_lds(                                 \
                (const void*)(Kb + (size_t)(k0s + r) * DK + uo),              \
                (void*)&KtL[BI][(wv * 16 + i * 8) * 64], 16, 0, 0);           \
            __builtin_amdgcn_global_load_lds(                                 \
                (const void*)(Vb + (size_t)r * SEQ + k0s + uo),               \
                (void*)&VtL[BI][(wv * 16 + i * 8) * 64], 16, 0, 0);           \
        }                                                                     \
    }

    STAGE(klo, 0);
    int cur = 0;

    for (int i = 0; i < nt; i++) {
        if (i + 1 < nt) {
            STAGE(klo + i + 1, cur ^ 1);      // next tile's loads in flight
            asm volatile("s_waitcnt vmcnt(4)" ::: "memory");  // tile i landed
        } else {
            asm volatile("s_waitcnt vmcnt(0)" ::: "memory");
        }
        __builtin_amdgcn_sched_barrier(0);
        __builtin_amdgcn_s_barrier();         // tile i visible to all waves
        __builtin_amdgcn_sched_barrier(0);

        const int k0 = (klo + i) << 6;

        // ---- V fragments once per tile (shared by both q-groups) ----
        short4_t vfr[4][4];
#pragma unroll
        for (int dt = 0; dt < 4; dt++)
#pragma unroll
            for (int kg = 0; kg < 4; kg++)
                vfr[dt][kg] = *(const short4_t*)&VtL[cur][(dt * 16 + fr) * 64 + vuoff[kg]];

        const bool mixed = B ? (k0 < nk0) : (k0 + 64 > nk0);

#pragma unroll
        for (int g = 0; g < 2; g++) {
            // ---- S^T = K Q^T (8 MFMA) ----
            f32x4 s[4];
#pragma unroll
            for (int kg = 0; kg < 4; kg++) {
                const int rr = (kg * 16 + fr) * 64;
                short8_t kc0 = *(const short8_t*)&KtL[cur][rr + u0];
                short8_t kc1 = *(const short8_t*)&KtL[cur][rr + u1];
                f32x4 a = fzero;
                a = MFMA(kc0, q_hi[g][0], a);
                a = MFMA(kc1, q_hi[g][1], a);
                s[kg] = a;
            }

            // ---- softmax ----
            short4_t pk[4];
            if (!mixed) {
#pragma unroll
                for (int kg = 0; kg < 4; kg++) {
                    union { short4_t v; unsigned short u[4]; } P;
#pragma unroll
                    for (int r = 0; r < 4; r++)
                        P.u[r] = f2bf(exp2f(fmaf(s[kg][r], C2, B2)));
                    pk[kg] = P.v;
                }
            } else {
#pragma unroll
                for (int kg = 0; kg < 4; kg++) {
                    union { short4_t v; unsigned short u[4]; } P;
#pragma unroll
                    for (int r = 0; r < 4; r++) {
                        int cb = (k0 + kg * 16 + fg * 4 + r) >= nk0;
                        float basev = (cb == B) ? B2 : -1e9f;
                        P.u[r] = f2bf(exp2f(fmaf(s[kg][r], C2, basev)));
                    }
                    pk[kg] = P.v;
                }
            }

            // ---- psum + PV (in-register) ----
#pragma unroll
            for (int kg = 0; kg < 4; kg++)
                acc_sum[g] = MFMA16(ones, pk[kg], acc_sum[g]);
#pragma unroll
            for (int dt = 0; dt < 4; dt++) {
                f32x4 acc = o_acc[g][dt];
#pragma unroll
                for (int kg = 0; kg < 4; kg++)
                    acc = MFMA16(vfr[dt][kg], pk[kg], acc);
                o_acc[g][dt] = acc;
            }
        }

        __builtin_amdgcn_sched_barrier(0);
        __builtin_amdgcn_s_barrier();         // buf[cur] fully consumed
        __builtin_amdgcn_sched_barrier(0);
        cur ^= 1;
    }
#undef STAGE

    // ---- epilogue: both q-groups; row q scatter via qorder; float4 stores ----
    const int b = bh >> 4, h = bh & 15;
#pragma unroll
    for (int g = 0; g < 2; g++) {
        const int qpos = qlo + g * 64 + wv * 16 + fr;
        if (qpos < qhi) {
            const int origq = qorder[(size_t)bh * SEQ + qpos];
            const float inv = 1.0f / acc_sum[g][0];
            float* orow = out + ((size_t)(b * SEQ + origq)) * DMODEL + h * DK + fg * 4;
#pragma unroll
            for (int dt = 0; dt < 4; dt++) {
                f32x4 v = o_acc[g][dt];
                v *= inv;
                *(f32x4*)(orow + dt * 16) = v;
            }
        }
    }
}

// ---------------------------------------------------------------------------

extern "C" void kernel_launch(void* const* d_in, const int* in_sizes, int n_in,
                              void* d_out, int out_size, void* d_ws, size_t ws_size,
                              hipStream_t stream)
{
    const float* query = (const float*)d_in[0];
    const float* key   = (const float*)d_in[1];
    const float* value = (const float*)d_in[2];
    const int* hash_q  = (const int*)d_in[3];
    const int* hash_k  = (const int*)d_in[4];
    const float* Wq    = (const float*)d_in[5];
    const float* bq    = (const float*)d_in[6];
    const float* Wk    = (const float*)d_in[7];
    const float* bk    = (const float*)d_in[8];
    const float* Wv    = (const float*)d_in[9];
    const float* bv    = (const float*)d_in[10];
    float* out = (float*)d_out;

    const size_t plane = (size_t)BATCH * NHEAD * SEQ * DK;   // 4,194,304 elems
    unsigned short* ws = (unsigned short*)d_ws;
    unsigned short* pQ    = ws;
    unsigned short* pK    = ws + plane;
    unsigned short* pVt   = ws + 2 * plane;                   // sorted V^T
    unsigned short* pVn   = ws + 3 * plane;                   // natural V^T
    unsigned short* Xslot = ws + 4 * plane;                   // 4M els
    unsigned short* Wslot = ws + 5 * plane;                   // 1M els
    int* ip = (int*)(ws + 5 * plane + (size_t)DMODEL * DMODEL);
    int* qorder = ip;                 // 32*2048
    int* korder = ip + 65536;
    int* qinv   = ip + 131072;
    int* kinv   = ip + 196608;
    int* cnts   = ip + 262144;        // 64

    bucket_kernel<<<64, 256, 0, stream>>>(hash_q, hash_k, qorder, korder,
                                          qinv, kinv, cnts);

    const int cvtBlocks = (int)((plane + (size_t)DMODEL * DMODEL) / 8 / 256);

    cvt_xw_kernel<<<cvtBlocks, 256, 0, stream>>>(query, Wq, Xslot, Wslot);
    proj_nat<0><<<512, 256, 0, stream>>>(Xslot, Wslot, bq, qinv, pQ);

    cvt_xw_kernel<<<cvtBlocks, 256, 0, stream>>>(key, Wk, Xslot, Wslot);
    proj_nat<0><<<512, 256, 0, stream>>>(Xslot, Wslot, bk, kinv, pK);

    cvt_xw_kernel<<<cvtBlocks, 256, 0, stream>>>(value, Wv, Xslot, Wslot);
    proj_nat<1><<<512, 256, 0, stream>>>(Xslot, Wslot, bv, kinv, pVn);

    vperm_kernel<<<2048, 256, 0, stream>>>(pVn, korder, pVt);

    lsh_attn_kernel<<<dim3(544), 256, 0, stream>>>(pQ, pK, pVt,
                                                   qorder, cnts, out);
}

// Round 14
// 132.986 us; speedup vs baseline: 1.0687x; 1.0158x over previous
//
#include <hip/hip_runtime.h>
#include <hip/hip_bf16.h>
#include <stdint.h>
#include <math.h>

#define NHEAD 16
#define DK 64
#define SEQ 2048
#define BATCH 2
#define DMODEL 1024

typedef __attribute__((ext_vector_type(8))) short short8_t;
typedef __attribute__((ext_vector_type(4))) short short4_t;
typedef __attribute__((ext_vector_type(4))) float f32x4;

#define MFMA(a, b, c) __builtin_amdgcn_mfma_f32_16x16x32_bf16(a, b, c, 0, 0, 0)
#define MFMA16(a, b, c) __builtin_amdgcn_mfma_f32_16x16x16bf16_1k(a, b, c, 0, 0, 0)

__device__ __forceinline__ unsigned short f2bf(float f) {
    union { __hip_bfloat16 b; unsigned short u; } c;
    c.b = __float2bfloat16(f);
    return c.u;
}

// ---------------------------------------------------------------------------
// bucket_kernel: per (bh, which) stable-partition indices by hash value.
// ---------------------------------------------------------------------------
__global__ __launch_bounds__(256) void bucket_kernel(
    const int* __restrict__ hq, const int* __restrict__ hk,
    int* __restrict__ qorder, int* __restrict__ korder,
    int* __restrict__ qinv, int* __restrict__ kinv, int* __restrict__ cnts)
{
    const int blk = blockIdx.x;          // 0..63
    const int bh = blk >> 1;
    const int which = blk & 1;
    const int* src = (which ? hk : hq) + (size_t)bh * SEQ;
    int* dst = (which ? korder : qorder) + (size_t)bh * SEQ;
    int* ivd = (which ? kinv : qinv) + (size_t)bh * SEQ;

    __shared__ int cnt[257];
    const int t = threadIdx.x;           // 0..255
    int h[8]; int c = 0;
#pragma unroll
    for (int j = 0; j < 8; j++) { h[j] = src[t * 8 + j]; c += (h[j] == 0); }
    cnt[t] = c;
    __syncthreads();
    if (t == 0) {
        int run = 0;
        for (int i = 0; i < 256; i++) { int v = cnt[i]; cnt[i] = run; run += v; }
        cnt[256] = run;
    }
    __syncthreads();
    const int nz = cnt[256];
    int zpos = cnt[t];
    int opos = nz + t * 8 - cnt[t];
#pragma unroll
    for (int j = 0; j < 8; j++) {
        int idx = t * 8 + j;
        if (h[j] == 0) { dst[zpos] = idx; ivd[idx] = zpos; zpos++; }
        else           { dst[opos] = idx; ivd[idx] = opos; opos++; }
    }
    if (t == 0) cnts[which * 32 + bh] = nz;
}

// ---------------------------------------------------------------------------
// cvt_xw: X (4M f32) -> bf16, W (1M f32) -> bf16.
// ---------------------------------------------------------------------------
__global__ __launch_bounds__(256) void cvt_xw_kernel(
    const float* __restrict__ X, const float* __restrict__ W,
    unsigned short* __restrict__ Xb, unsigned short* __restrict__ Wb)
{
    const size_t t = (size_t)blockIdx.x * 256 + threadIdx.x;
    const float* src;
    unsigned short* dst;
    size_t i8;
    if (t < 524288) { src = X; dst = Xb; i8 = t * 8; }
    else            { src = W; dst = Wb; i8 = (t - 524288) * 8; }
    f32x4 v0 = *(const f32x4*)(src + i8);
    f32x4 v1 = *(const f32x4*)(src + i8 + 4);
    union { short8_t v; unsigned short u[8]; } o;
#pragma unroll
    for (int j = 0; j < 4; j++) {
        o.u[j]     = f2bf(v0[j]);
        o.u[4 + j] = f2bf(v1[j]);
    }
    *(short8_t*)(dst + i8) = o.v;
}

// ---------------------------------------------------------------------------
// proj_nat (r11-proven): natural-order GEMM, tile 128(A) x 64(B), BK=64,
// double-buffered global_load_lds with counted vmcnt. Grid 512, XCD-grouped.
// MODE 0: A=X, B=W. C[gm][od]; row-scatter via inv -> dst[bh][pos][d] (Q/K).
// MODE 1: A=W, B=X. C[od][gm]; natural store -> dst[bh][d][gm] (V^T natural).
// ---------------------------------------------------------------------------
template <int MODE>
__global__ __launch_bounds__(256) void proj_nat(
    const unsigned short* __restrict__ Xb,   // [4096][1024]
    const unsigned short* __restrict__ Wb,   // [1024][1024]
    const float* __restrict__ bias,
    const int* __restrict__ inv,             // [32][2048] (MODE 0)
    unsigned short* __restrict__ dst)
{
    __shared__ unsigned short At[2][128 * 64];
    __shared__ unsigned short Bt[2][64 * 64];

    const int tid = threadIdx.x;
    const int lane = tid & 63;
    const int wv = tid >> 6;
    const int fr = lane & 15;
    const int fg = lane >> 4;
    const int srw = lane >> 3;
    const int su = lane & 7;

    const int flat = blockIdx.x;            // 0..511
    const int xg = flat & 7;                // XCD group (round-robin dispatch)
    const int j = flat >> 3;                // 0..63

    const unsigned short* Ap; const unsigned short* Bp;
    int m0, n0;
    if constexpr (MODE == 0) {
        Ap = Xb; Bp = Wb;
        m0 = ((xg << 2) + (j >> 4)) * 128;
        n0 = (j & 15) * 64;
    } else {
        Ap = Wb; Bp = Xb;
        m0 = (j & 7) * 128;
        n0 = ((xg << 3) + (j >> 3)) * 64;
    }

    const unsigned short* aS[4]; const unsigned short* bS[2];
#pragma unroll
    for (int i = 0; i < 4; i++) {
        int r = wv * 32 + i * 8 + srw;
        aS[i] = Ap + (size_t)(m0 + r) * DMODEL + ((su ^ (r & 7)) << 3);
    }
#pragma unroll
    for (int i = 0; i < 2; i++) {
        int r = wv * 16 + i * 8 + srw;
        bS[i] = Bp + (size_t)(n0 + r) * DMODEL + ((su ^ (r & 7)) << 3);
    }

    f32x4 acc[2][4];
    const f32x4 fzero = {0.f, 0.f, 0.f, 0.f};
#pragma unroll
    for (int mf = 0; mf < 2; mf++)
#pragma unroll
        for (int nf = 0; nf < 4; nf++) acc[mf][nf] = fzero;

#define PSTAGE(K0, BI)                                                        \
    {                                                                         \
        _Pragma("unroll")                                                     \
        for (int i = 0; i < 4; i++)                                           \
            __builtin_amdgcn_global_load_lds(                                 \
                (const void*)(aS[i] + (K0)),                                  \
                (void*)&At[BI][(wv * 32 + i * 8) * 64], 16, 0, 0);            \
        _Pragma("unroll")                                                     \
        for (int i = 0; i < 2; i++)                                           \
            __builtin_amdgcn_global_load_lds(                                 \
                (const void*)(bS[i] + (K0)),                                  \
                (void*)&Bt[BI][(wv * 16 + i * 8) * 64], 16, 0, 0);            \
    }

    PSTAGE(0, 0);
    int cur = 0;

    for (int kk = 0; kk < 16; kk++) {
        if (kk < 15) {
            PSTAGE((kk + 1) * 64, cur ^ 1);
            asm volatile("s_waitcnt vmcnt(6)" ::: "memory");  // tile kk landed
        } else {
            asm volatile("s_waitcnt vmcnt(0)" ::: "memory");
        }
        __builtin_amdgcn_sched_barrier(0);
        __builtin_amdgcn_s_barrier();
        __builtin_amdgcn_sched_barrier(0);

        short8_t a[2][2], b[4][2];
#pragma unroll
        for (int mf = 0; mf < 2; mf++)
#pragma unroll
            for (int ks = 0; ks < 2; ks++) {
                int r = wv * 32 + mf * 16 + fr;
                int u = (ks * 4 + fg) ^ (fr & 7);
                a[mf][ks] = *(const short8_t*)&At[cur][r * 64 + u * 8];
            }
#pragma unroll
        for (int nf = 0; nf < 4; nf++)
#pragma unroll
            for (int ks = 0; ks < 2; ks++) {
                int r = nf * 16 + fr;
                int u = (ks * 4 + fg) ^ (fr & 7);
                b[nf][ks] = *(const short8_t*)&Bt[cur][r * 64 + u * 8];
            }
#pragma unroll
        for (int ks = 0; ks < 2; ks++)
#pragma unroll
            for (int mf = 0; mf < 2; mf++)
#pragma unroll
                for (int nf = 0; nf < 4; nf++)
                    acc[mf][nf] = MFMA(a[mf][ks], b[nf][ks], acc[mf][nf]);

        __builtin_amdgcn_sched_barrier(0);
        __builtin_amdgcn_s_barrier();      // all reads of buf[cur] done
        __builtin_amdgcn_sched_barrier(0);
        cur ^= 1;
    }
#undef PSTAGE

    if constexpr (MODE == 0) {
        const int hh = n0 >> 6;
#pragma unroll
        for (int mf = 0; mf < 2; mf++)
#pragma unroll
            for (int r = 0; r < 4; r++) {
                int gm = m0 + wv * 32 + mf * 16 + fg * 4 + r;   // b*2048+l
                int bb = gm >> 11;
                int bh = bb * NHEAD + hh;
                int pos = inv[(size_t)bh * SEQ + (gm & (SEQ - 1))];
                unsigned short* drow = dst + ((size_t)bh * SEQ + pos) * DK;
#pragma unroll
                for (int nf = 0; nf < 4; nf++) {
                    float v = acc[mf][nf][r] + bias[n0 + nf * 16 + fr];
                    drow[nf * 16 + fr] = f2bf(v);
                }
            }
    } else {
        const int bb = n0 >> 11;
#pragma unroll
        for (int mf = 0; mf < 2; mf++)
#pragma unroll
            for (int r = 0; r < 4; r++) {
                int od = m0 + wv * 32 + mf * 16 + fg * 4 + r;   // h*64+d
                int h = od >> 6;
                int bh = bb * NHEAD + h;
                float bv = bias[od];
                unsigned short* drow =
                    dst + ((size_t)bh * DK + (od & 63)) * SEQ + (n0 & (SEQ - 1));
#pragma unroll
                for (int nf = 0; nf < 4; nf++) {
                    float v = acc[mf][nf][r] + bv;
                    drow[nf * 16 + fr] = f2bf(v);
                }
            }
    }
}

// ---------------------------------------------------------------------------
// vperm: Vs[bh][d][pos] = Vn[bh][d][korder[bh][pos]]  (gather along keys)
// ---------------------------------------------------------------------------
__global__ __launch_bounds__(256) void vperm_kernel(
    const unsigned short* __restrict__ Vn, const int* __restrict__ korder,
    unsigned short* __restrict__ Vs)
{
    const int blk = blockIdx.x;       // 0..2047 = bh*64 + d
    const int bh = blk >> 6;
    const int d  = blk & 63;
    const int t = threadIdx.x;        // pos = t*8
    const int* kop = korder + (size_t)bh * SEQ + t * 8;
    const unsigned short* src = Vn + ((size_t)bh * DK + d) * SEQ;
    union { short8_t v; unsigned short u[8]; } o;
#pragma unroll
    for (int j = 0; j < 8; j++) o.u[j] = src[kop[j]];
    *(short8_t*)(Vs + ((size_t)bh * DK + d) * SEQ + t * 8) = o.v;
}

// ---------------------------------------------------------------------------
// LSH flash attention: bucket-sorted, bucket-aligned 64-row q-slots, swapped
// QK^T, in-register PV (16x16x16), psum via MFMA. TRIPLE-buffered rotation:
// ONE barrier per tile, depth-2 prefetch, counted vmcnt. STAGE placed AFTER
// the barrier so the single barrier protects both RAW and WAR hazards.
// Grid: 1056 = 8 XCD x (4 heads x 33 slots).
// ---------------------------------------------------------------------------
__global__ __launch_bounds__(256, 3) void lsh_attn_kernel(
    const unsigned short* __restrict__ Qs,
    const unsigned short* __restrict__ Ks, const unsigned short* __restrict__ Vst,
    const int* __restrict__ qorder, const int* __restrict__ cnts,
    float* __restrict__ out)
{
    __shared__ unsigned short KtL[3][64 * 64];
    __shared__ unsigned short VtL[3][64 * 64];

    const int tid = threadIdx.x;
    const int lane = tid & 63;
    const int wv = tid >> 6;
    const int fr = lane & 15;
    const int fg = lane >> 4;

    const int flat = blockIdx.x;
    const int xcd = flat & 7;
    const int s2 = flat >> 3;                 // 0..131
    const int bh = (xcd << 2) + (s2 / 33);    // b*16 + h
    const int slot = s2 % 33;

    const int nq0 = cnts[bh];
    const int nk0 = cnts[32 + bh];
    const int c0 = (nq0 + 63) >> 6;           // q-tiles covering bucket 0

    int B, qlo, qhi;
    if (slot < c0) {
        B = 0; qlo = slot << 6; qhi = min(qlo + 64, nq0);
    } else {
        B = 1; qlo = nq0 + ((slot - c0) << 6);
        if (qlo >= SEQ) return;               // block-uniform: safe w/ barriers
        qhi = min(qlo + 64, SEQ);
    }
    const int klo = B ? (nk0 >> 6) : 0;
    const int khi = B ? (SEQ >> 6) : ((nk0 + 63) >> 6);
    const int nt = khi - klo;

    const size_t base = (size_t)bh * SEQ * DK;
    const unsigned short* Kb = Ks + base;                    // [pos][d]
    const unsigned short* Vb = Vst + (size_t)bh * DK * SEQ;  // [d][pos]

    const int srw = lane >> 3;
    const int su = lane & 7;

    // Q fragments (B-operand of swapped QK: lane fr = q-row qlo + wv*16 + fr)
    short8_t q_hi[2];
    {
        const size_t ro = base + (size_t)(qlo + wv * 16 + fr) * DK;
        q_hi[0] = *(const short8_t*)(Qs + ro + fg * 8);
        q_hi[1] = *(const short8_t*)(Qs + ro + 32 + fg * 8);
    }

    const int swz = fr & 7;
    const int u0 = ((fg ^ swz) << 3);
    const int u1 = (((4 + fg) ^ swz) << 3);
    int vuoff[4];
#pragma unroll
    for (int kg = 0; kg < 4; kg++)
        vuoff[kg] = (((kg * 2 + (fg >> 1)) ^ swz) << 3) + ((fg & 1) << 2);

    const float C2 = 0.18033688011112042f;    // 0.125 * log2(e)
    const float B2 = -14.426950408889634f;    // -10 * log2(e)

    const short4_t ones = {(short)0x3F80, (short)0x3F80, (short)0x3F80, (short)0x3F80};
    f32x4 acc_sum;
    f32x4 o_acc[4];
    const f32x4 fzero = {0.f, 0.f, 0.f, 0.f};
    acc_sum = fzero;
#pragma unroll
    for (int t = 0; t < 4; t++) o_acc[t] = fzero;

#define STAGE(T, BI)                                                          \
    {                                                                         \
        const int k0s = (T) << 6;                                             \
        _Pragma("unroll")                                                     \
        for (int i = 0; i < 2; i++) {                                         \
            const int r = wv * 16 + i * 8 + srw;                              \
            const int uo = ((su ^ (r & 7)) << 3);                             \
            __builtin_amdgcn_global_load_lds(                                 \
                (const void*)(Kb + (size_t)(k0s + r) * DK + uo),              \
                (void*)&KtL[BI][(wv * 16 + i * 8) * 64], 16, 0, 0);           \
            __builtin_amdgcn_global_load_lds(                                 \
                (const void*)(Vb + (size_t)r * SEQ + k0s + uo),               \
                (void*)&VtL[BI][(wv * 16 + i * 8) * 64], 16, 0, 0);           \
        }                                                                     \
    }

    STAGE(klo, 0);
    if (nt > 1) STAGE(klo + 1, 1);
    int cur = 0;

    for (int i = 0; i < nt; i++) {
        // tile i landed? (FIFO: with tiles {i, i+1} outstanding = 8 loads,
        // vmcnt(4) completes the oldest 4 = tile i)
        if (i + 1 < nt) {
            asm volatile("s_waitcnt vmcnt(4)" ::: "memory");
        } else {
            asm volatile("s_waitcnt vmcnt(0)" ::: "memory");
        }
        __builtin_amdgcn_sched_barrier(0);
        __builtin_amdgcn_s_barrier();         // RAW: tile i visible; WAR: all
        __builtin_amdgcn_sched_barrier(0);    // waves done reading buf[cur+2]

        if (i + 2 < nt) {
            int nb = cur + 2; if (nb >= 3) nb -= 3;
            STAGE(klo + i + 2, nb);           // depth-2 prefetch
        }

        const int k0 = (klo + i) << 6;

        // ---- V fragments into regs early (independent of S) ----
        short4_t vfr[4][4];
#pragma unroll
        for (int dt = 0; dt < 4; dt++)
#pragma unroll
            for (int kg = 0; kg < 4; kg++)
                vfr[dt][kg] = *(const short4_t*)&VtL[cur][(dt * 16 + fr) * 64 + vuoff[kg]];

        // ---- S^T = K Q^T (8 MFMA; A = K rows, B = Q) ----
        f32x4 s[4];
#pragma unroll
        for (int kg = 0; kg < 4; kg++) {
            const int rr = (kg * 16 + fr) * 64;
            short8_t kc0 = *(const short8_t*)&KtL[cur][rr + u0];
            short8_t kc1 = *(const short8_t*)&KtL[cur][rr + u1];
            f32x4 a = fzero;
            a = MFMA(kc0, q_hi[0], a);
            a = MFMA(kc1, q_hi[1], a);
            s[kg] = a;
        }

        // ---- softmax: p = exp2(s*C2 + B2); boundary tile masks by position ----
        short4_t pk[4];
        const bool mixed = B ? (k0 < nk0) : (k0 + 64 > nk0);
        if (!mixed) {
#pragma unroll
            for (int kg = 0; kg < 4; kg++) {
                union { short4_t v; unsigned short u[4]; } P;
#pragma unroll
                for (int r = 0; r < 4; r++)
                    P.u[r] = f2bf(exp2f(fmaf(s[kg][r], C2, B2)));
                pk[kg] = P.v;
            }
        } else {
#pragma unroll
            for (int kg = 0; kg < 4; kg++) {
                union { short4_t v; unsigned short u[4]; } P;
#pragma unroll
                for (int r = 0; r < 4; r++) {
                    int cb = (k0 + kg * 16 + fg * 4 + r) >= nk0;
                    float basev = (cb == B) ? B2 : -1e9f;
                    P.u[r] = f2bf(exp2f(fmaf(s[kg][r], C2, basev)));
                }
                pk[kg] = P.v;
            }
        }

        // ---- psum via MFMA: acc_sum[.][q] += sum_k P^T[k][q] ----
#pragma unroll
        for (int kg = 0; kg < 4; kg++)
            acc_sum = MFMA16(ones, pk[kg], acc_sum);

        // ---- O^T += V^T P^T (in-register A and B) ----
#pragma unroll
        for (int dt = 0; dt < 4; dt++) {
            f32x4 acc = o_acc[dt];
#pragma unroll
            for (int kg = 0; kg < 4; kg++)
                acc = MFMA16(vfr[dt][kg], pk[kg], acc);
            o_acc[dt] = acc;
        }

        cur = cur + 1; if (cur >= 3) cur -= 3;
    }
#undef STAGE

    // acc_sum rows are identical; element 0 already holds the full psum for q=fr
    const float psum = acc_sum[0];

    // ---- epilogue: row q=fr scatter via qorder; cols contiguous -> float4 ----
    const int b = bh >> 4, h = bh & 15;
    const int qpos = qlo + wv * 16 + fr;
    if (qpos < qhi) {
        const int origq = qorder[(size_t)bh * SEQ + qpos];
        const float inv = 1.0f / psum;
        float* orow = out + ((size_t)(b * SEQ + origq)) * DMODEL + h * DK + fg * 4;
#pragma unroll
        for (int dt = 0; dt < 4; dt++) {
            f32x4 v = o_acc[dt];
            v *= inv;
            *(f32x4*)(orow + dt * 16) = v;
        }
    }
}

// ---------------------------------------------------------------------------

extern "C" void kernel_launch(void* const* d_in, const int* in_sizes, int n_in,
                              void* d_out, int out_size, void* d_ws, size_t ws_size,
                              hipStream_t stream)
{
    const float* query = (const float*)d_in[0];
    const float* key   = (const float*)d_in[1];
    const float* value = (const float*)d_in[2];
    const int* hash_q  = (const int*)d_in[3];
    const int* hash_k  = (const int*)d_in[4];
    const float* Wq    = (const float*)d_in[5];
    const float* bq    = (const float*)d_in[6];
    const float* Wk    = (const float*)d_in[7];
    const float* bk    = (const float*)d_in[8];
    const float* Wv    = (const float*)d_in[9];
    const float* bv    = (const float*)d_in[10];
    float* out = (float*)d_out;

    const size_t plane = (size_t)BATCH * NHEAD * SEQ * DK;   // 4,194,304 elems
    unsigned short* ws = (unsigned short*)d_ws;
    unsigned short* pQ    = ws;
    unsigned short* pK    = ws + plane;
    unsigned short* pVt   = ws + 2 * plane;                   // sorted V^T
    unsigned short* pVn   = ws + 3 * plane;                   // natural V^T
    unsigned short* Xslot = ws + 4 * plane;                   // 4M els
    unsigned short* Wslot = ws + 5 * plane;                   // 1M els
    int* ip = (int*)(ws + 5 * plane + (size_t)DMODEL * DMODEL);
    int* qorder = ip;                 // 32*2048
    int* korder = ip + 65536;
    int* qinv   = ip + 131072;
    int* kinv   = ip + 196608;
    int* cnts   = ip + 262144;        // 64

    bucket_kernel<<<64, 256, 0, stream>>>(hash_q, hash_k, qorder, korder,
                                          qinv, kinv, cnts);

    const int cvtBlocks = (int)((plane + (size_t)DMODEL * DMODEL) / 8 / 256);

    cvt_xw_kernel<<<cvtBlocks, 256, 0, stream>>>(query, Wq, Xslot, Wslot);
    proj_nat<0><<<512, 256, 0, stream>>>(Xslot, Wslot, bq, qinv, pQ);

    cvt_xw_kernel<<<cvtBlocks, 256, 0, stream>>>(key, Wk, Xslot, Wslot);
    proj_nat<0><<<512, 256, 0, stream>>>(Xslot, Wslot, bk, kinv, pK);

    cvt_xw_kernel<<<cvtBlocks, 256, 0, stream>>>(value, Wv, Xslot, Wslot);
    proj_nat<1><<<512, 256, 0, stream>>>(Xslot, Wslot, bv, kinv, pVn);

    vperm_kernel<<<2048, 256, 0, stream>>>(pVn, korder, pVt);

    lsh_attn_kernel<<<dim3(1056), 256, 0, stream>>>(pQ, pK, pVt,
                                                    qorder, cnts, out);
}

// Round 15
// 105.600 us; speedup vs baseline: 1.3458x; 1.2593x over previous
//
#include <hip/hip_runtime.h>
#include <hip/hip_bf16.h>
#include <stdint.h>
#include <math.h>

#define NHEAD 16
#define DK 64
#define SEQ 2048
#define BATCH 2
#define DMODEL 1024

typedef __attribute__((ext_vector_type(8))) short short8_t;
typedef __attribute__((ext_vector_type(4))) short short4_t;
typedef __attribute__((ext_vector_type(4))) float f32x4;

#define MFMA(a, b, c) __builtin_amdgcn_mfma_f32_16x16x32_bf16(a, b, c, 0, 0, 0)
#define MFMA16(a, b, c) __builtin_amdgcn_mfma_f32_16x16x16bf16_1k(a, b, c, 0, 0, 0)

__device__ __forceinline__ unsigned short f2bf(float f) {
    union { __hip_bfloat16 b; unsigned short u; } c;
    c.b = __float2bfloat16(f);
    return c.u;
}

// ---------------------------------------------------------------------------
// bucket_cvt_kernel: blocks 0..63 = bucket partition; blocks 64.. = convert
// all 3 X inputs + all 3 W matrices to bf16 (independent work, one launch).
// ---------------------------------------------------------------------------
__global__ __launch_bounds__(256) void bucket_cvt_kernel(
    const int* __restrict__ hq, const int* __restrict__ hk,
    int* __restrict__ qorder, int* __restrict__ korder,
    int* __restrict__ qinv, int* __restrict__ kinv, int* __restrict__ cnts,
    const float* __restrict__ X0, const float* __restrict__ X1,
    const float* __restrict__ X2,
    const float* __restrict__ W0, const float* __restrict__ W1,
    const float* __restrict__ W2,
    unsigned short* __restrict__ xo0, unsigned short* __restrict__ xo1,
    unsigned short* __restrict__ xo2,
    unsigned short* __restrict__ wo0, unsigned short* __restrict__ wo1,
    unsigned short* __restrict__ wo2)
{
    __shared__ int cnt[257];
    const int t = threadIdx.x;
    if (blockIdx.x < 64) {
        const int blk = blockIdx.x;
        const int bh = blk >> 1;
        const int which = blk & 1;
        const int* src = (which ? hk : hq) + (size_t)bh * SEQ;
        int* dst = (which ? korder : qorder) + (size_t)bh * SEQ;
        int* ivd = (which ? kinv : qinv) + (size_t)bh * SEQ;

        int h[8]; int c = 0;
#pragma unroll
        for (int j = 0; j < 8; j++) { h[j] = src[t * 8 + j]; c += (h[j] == 0); }
        cnt[t] = c;
        __syncthreads();
        if (t == 0) {
            int run = 0;
            for (int i = 0; i < 256; i++) { int v = cnt[i]; cnt[i] = run; run += v; }
            cnt[256] = run;
        }
        __syncthreads();
        const int nz = cnt[256];
        int zpos = cnt[t];
        int opos = nz + t * 8 - cnt[t];
#pragma unroll
        for (int j = 0; j < 8; j++) {
            int idx = t * 8 + j;
            if (h[j] == 0) { dst[zpos] = idx; ivd[idx] = zpos; zpos++; }
            else           { dst[opos] = idx; ivd[idx] = opos; opos++; }
        }
        if (t == 0) cnts[which * 32 + bh] = nz;
        return;
    }

    // cvt section: g in [0, 1,966,080) groups of 8 elems
    const size_t g = (size_t)(blockIdx.x - 64) * 256 + t;
    const float* s; unsigned short* d; size_t off;
    if (g < 1572864) {
        int which = (int)(g / 524288);
        off = (g % 524288) * 8;
        s = which == 0 ? X0 : (which == 1 ? X1 : X2);
        d = which == 0 ? xo0 : (which == 1 ? xo1 : xo2);
    } else {
        size_t g2 = g - 1572864;
        int which = (int)(g2 / 131072);
        off = (g2 % 131072) * 8;
        s = which == 0 ? W0 : (which == 1 ? W1 : W2);
        d = which == 0 ? wo0 : (which == 1 ? wo1 : wo2);
    }
    f32x4 v0 = *(const f32x4*)(s + off);
    f32x4 v1 = *(const f32x4*)(s + off + 4);
    union { short8_t v; unsigned short u[8]; } o;
#pragma unroll
    for (int j = 0; j < 4; j++) {
        o.u[j]     = f2bf(v0[j]);
        o.u[4 + j] = f2bf(v1[j]);
    }
    *(short8_t*)(d + off) = o.v;
}

// ---------------------------------------------------------------------------
// bucket_kernel (fallback path) — identical logic, standalone.
// ---------------------------------------------------------------------------
__global__ __launch_bounds__(256) void bucket_kernel(
    const int* __restrict__ hq, const int* __restrict__ hk,
    int* __restrict__ qorder, int* __restrict__ korder,
    int* __restrict__ qinv, int* __restrict__ kinv, int* __restrict__ cnts)
{
    const int blk = blockIdx.x;
    const int bh = blk >> 1;
    const int which = blk & 1;
    const int* src = (which ? hk : hq) + (size_t)bh * SEQ;
    int* dst = (which ? korder : qorder) + (size_t)bh * SEQ;
    int* ivd = (which ? kinv : qinv) + (size_t)bh * SEQ;

    __shared__ int cnt[257];
    const int t = threadIdx.x;
    int h[8]; int c = 0;
#pragma unroll
    for (int j = 0; j < 8; j++) { h[j] = src[t * 8 + j]; c += (h[j] == 0); }
    cnt[t] = c;
    __syncthreads();
    if (t == 0) {
        int run = 0;
        for (int i = 0; i < 256; i++) { int v = cnt[i]; cnt[i] = run; run += v; }
        cnt[256] = run;
    }
    __syncthreads();
    const int nz = cnt[256];
    int zpos = cnt[t];
    int opos = nz + t * 8 - cnt[t];
#pragma unroll
    for (int j = 0; j < 8; j++) {
        int idx = t * 8 + j;
        if (h[j] == 0) { dst[zpos] = idx; ivd[idx] = zpos; zpos++; }
        else           { dst[opos] = idx; ivd[idx] = opos; opos++; }
    }
    if (t == 0) cnts[which * 32 + bh] = nz;
}

// ---------------------------------------------------------------------------
// cvt_xw (fallback path): X (4M f32) -> bf16, W (1M f32) -> bf16.
// ---------------------------------------------------------------------------
__global__ __launch_bounds__(256) void cvt_xw_kernel(
    const float* __restrict__ X, const float* __restrict__ W,
    unsigned short* __restrict__ Xb, unsigned short* __restrict__ Wb)
{
    const size_t t = (size_t)blockIdx.x * 256 + threadIdx.x;
    const float* src;
    unsigned short* dst;
    size_t i8;
    if (t < 524288) { src = X; dst = Xb; i8 = t * 8; }
    else            { src = W; dst = Wb; i8 = (t - 524288) * 8; }
    f32x4 v0 = *(const f32x4*)(src + i8);
    f32x4 v1 = *(const f32x4*)(src + i8 + 4);
    union { short8_t v; unsigned short u[8]; } o;
#pragma unroll
    for (int j = 0; j < 4; j++) {
        o.u[j]     = f2bf(v0[j]);
        o.u[4 + j] = f2bf(v1[j]);
    }
    *(short8_t*)(dst + i8) = o.v;
}

// ---------------------------------------------------------------------------
// proj_kernel: r11-proven GEMM body, runtime group select.
// grp = grpBase + blockIdx.x/512; local = blockIdx.x & 511.
// grp 0: Q = Xq @ Wq^T (row-scatter via qinv)   -> pQ[bh][pos][d]
// grp 1: K = Xk @ Wk^T (row-scatter via kinv)   -> pK[bh][pos][d]
// grp 2: V^T natural = Wv @ Xv^T                -> pVn[bh][d][gm]
// Tile 128(A) x 64(B), BK=64, dbuf global_load_lds + counted vmcnt,
// XCD-grouped on local&7.
// ---------------------------------------------------------------------------
__global__ __launch_bounds__(256) void proj_kernel(
    const unsigned short* __restrict__ Xq, const unsigned short* __restrict__ Xk,
    const unsigned short* __restrict__ Xv,
    const unsigned short* __restrict__ Wq, const unsigned short* __restrict__ Wk,
    const unsigned short* __restrict__ Wv,
    const float* __restrict__ bq, const float* __restrict__ bk,
    const float* __restrict__ bv,
    const int* __restrict__ qinv, const int* __restrict__ kinv,
    unsigned short* __restrict__ pQ, unsigned short* __restrict__ pK,
    unsigned short* __restrict__ pVn, int grpBase)
{
    __shared__ unsigned short At[2][128 * 64];
    __shared__ unsigned short Bt[2][64 * 64];

    const int tid = threadIdx.x;
    const int lane = tid & 63;
    const int wv = tid >> 6;
    const int fr = lane & 15;
    const int fg = lane >> 4;
    const int srw = lane >> 3;
    const int su = lane & 7;

    const int grp = grpBase + (blockIdx.x >> 9);
    const int local = blockIdx.x & 511;
    const int xg = local & 7;               // XCD group
    const int j = local >> 3;               // 0..63
    const bool mode1 = (grp == 2);

    const unsigned short* Xb = grp == 0 ? Xq : (grp == 1 ? Xk : Xv);
    const unsigned short* Wb = grp == 0 ? Wq : (grp == 1 ? Wk : Wv);
    const float* bias = grp == 0 ? bq : (grp == 1 ? bk : bv);
    const int* inv = grp == 0 ? qinv : kinv;
    unsigned short* dst = grp == 0 ? pQ : (grp == 1 ? pK : pVn);

    const unsigned short* Ap; const unsigned short* Bp;
    int m0, n0;
    if (!mode1) {
        Ap = Xb; Bp = Wb;
        m0 = ((xg << 2) + (j >> 4)) * 128;
        n0 = (j & 15) * 64;
    } else {
        Ap = Wb; Bp = Xb;
        m0 = (j & 7) * 128;
        n0 = ((xg << 3) + (j >> 3)) * 64;
    }

    const unsigned short* aS[4]; const unsigned short* bS[2];
#pragma unroll
    for (int i = 0; i < 4; i++) {
        int r = wv * 32 + i * 8 + srw;
        aS[i] = Ap + (size_t)(m0 + r) * DMODEL + ((su ^ (r & 7)) << 3);
    }
#pragma unroll
    for (int i = 0; i < 2; i++) {
        int r = wv * 16 + i * 8 + srw;
        bS[i] = Bp + (size_t)(n0 + r) * DMODEL + ((su ^ (r & 7)) << 3);
    }

    f32x4 acc[2][4];
    const f32x4 fzero = {0.f, 0.f, 0.f, 0.f};
#pragma unroll
    for (int mf = 0; mf < 2; mf++)
#pragma unroll
        for (int nf = 0; nf < 4; nf++) acc[mf][nf] = fzero;

#define PSTAGE(K0, BI)                                                        \
    {                                                                         \
        _Pragma("unroll")                                                     \
        for (int i = 0; i < 4; i++)                                           \
            __builtin_amdgcn_global_load_lds(                                 \
                (const void*)(aS[i] + (K0)),                                  \
                (void*)&At[BI][(wv * 32 + i * 8) * 64], 16, 0, 0);            \
        _Pragma("unroll")                                                     \
        for (int i = 0; i < 2; i++)                                           \
            __builtin_amdgcn_global_load_lds(                                 \
                (const void*)(bS[i] + (K0)),                                  \
                (void*)&Bt[BI][(wv * 16 + i * 8) * 64], 16, 0, 0);            \
    }

    PSTAGE(0, 0);
    int cur = 0;

    for (int kk = 0; kk < 16; kk++) {
        if (kk < 15) {
            PSTAGE((kk + 1) * 64, cur ^ 1);
            asm volatile("s_waitcnt vmcnt(6)" ::: "memory");  // tile kk landed
        } else {
            asm volatile("s_waitcnt vmcnt(0)" ::: "memory");
        }
        __builtin_amdgcn_sched_barrier(0);
        __builtin_amdgcn_s_barrier();
        __builtin_amdgcn_sched_barrier(0);

        short8_t a[2][2], b[4][2];
#pragma unroll
        for (int mf = 0; mf < 2; mf++)
#pragma unroll
            for (int ks = 0; ks < 2; ks++) {
                int r = wv * 32 + mf * 16 + fr;
                int u = (ks * 4 + fg) ^ (fr & 7);
                a[mf][ks] = *(const short8_t*)&At[cur][r * 64 + u * 8];
            }
#pragma unroll
        for (int nf = 0; nf < 4; nf++)
#pragma unroll
            for (int ks = 0; ks < 2; ks++) {
                int r = nf * 16 + fr;
                int u = (ks * 4 + fg) ^ (fr & 7);
                b[nf][ks] = *(const short8_t*)&Bt[cur][r * 64 + u * 8];
            }
#pragma unroll
        for (int ks = 0; ks < 2; ks++)
#pragma unroll
            for (int mf = 0; mf < 2; mf++)
#pragma unroll
                for (int nf = 0; nf < 4; nf++)
                    acc[mf][nf] = MFMA(a[mf][ks], b[nf][ks], acc[mf][nf]);

        __builtin_amdgcn_sched_barrier(0);
        __builtin_amdgcn_s_barrier();      // all reads of buf[cur] done
        __builtin_amdgcn_sched_barrier(0);
        cur ^= 1;
    }
#undef PSTAGE

    if (!mode1) {
        const int hh = n0 >> 6;
#pragma unroll
        for (int mf = 0; mf < 2; mf++)
#pragma unroll
            for (int r = 0; r < 4; r++) {
                int gm = m0 + wv * 32 + mf * 16 + fg * 4 + r;   // b*2048+l
                int bb = gm >> 11;
                int bh = bb * NHEAD + hh;
                int pos = inv[(size_t)bh * SEQ + (gm & (SEQ - 1))];
                unsigned short* drow = dst + ((size_t)bh * SEQ + pos) * DK;
#pragma unroll
                for (int nf = 0; nf < 4; nf++) {
                    float v = acc[mf][nf][r] + bias[n0 + nf * 16 + fr];
                    drow[nf * 16 + fr] = f2bf(v);
                }
            }
    } else {
        const int bb = n0 >> 11;
#pragma unroll
        for (int mf = 0; mf < 2; mf++)
#pragma unroll
            for (int r = 0; r < 4; r++) {
                int od = m0 + wv * 32 + mf * 16 + fg * 4 + r;   // h*64+d
                int h = od >> 6;
                int bh = bb * NHEAD + h;
                float bvv = bias[od];
                unsigned short* drow =
                    dst + ((size_t)bh * DK + (od & 63)) * SEQ + (n0 & (SEQ - 1));
#pragma unroll
                for (int nf = 0; nf < 4; nf++) {
                    float v = acc[mf][nf][r] + bvv;
                    drow[nf * 16 + fr] = f2bf(v);
                }
            }
    }
}

// ---------------------------------------------------------------------------
// vperm: Vs[bh][d][pos] = Vn[bh][d][korder[bh][pos]]  (gather along keys)
// ---------------------------------------------------------------------------
__global__ __launch_bounds__(256) void vperm_kernel(
    const unsigned short* __restrict__ Vn, const int* __restrict__ korder,
    unsigned short* __restrict__ Vs)
{
    const int blk = blockIdx.x;       // 0..2047 = bh*64 + d
    const int bh = blk >> 6;
    const int d  = blk & 63;
    const int t = threadIdx.x;        // pos = t*8
    const int* kop = korder + (size_t)bh * SEQ + t * 8;
    const unsigned short* src = Vn + ((size_t)bh * DK + d) * SEQ;
    union { short8_t v; unsigned short u[8]; } o;
#pragma unroll
    for (int j = 0; j < 8; j++) o.u[j] = src[kop[j]];
    *(short8_t*)(Vs + ((size_t)bh * DK + d) * SEQ + t * 8) = o.v;
}

// ---------------------------------------------------------------------------
// LSH flash attention (r12-proven best: 57.2us): bucket-sorted, bucket-
// aligned 64-row q-slots, swapped QK^T, in-register PV (16x16x16), psum via
// MFMA, double-buffer + counted-vmcnt 2-phase, launch_bounds(256,4).
// ---------------------------------------------------------------------------
__global__ __launch_bounds__(256, 4) void lsh_attn_kernel(
    const unsigned short* __restrict__ Qs,
    const unsigned short* __restrict__ Ks, const unsigned short* __restrict__ Vst,
    const int* __restrict__ qorder, const int* __restrict__ cnts,
    float* __restrict__ out)
{
    __shared__ unsigned short KtL[2][64 * 64];
    __shared__ unsigned short VtL[2][64 * 64];

    const int tid = threadIdx.x;
    const int lane = tid & 63;
    const int wv = tid >> 6;
    const int fr = lane & 15;
    const int fg = lane >> 4;

    // XCD-grouped mapping: 1056 = 8 XCD x (4 heads x 33 slots)
    const int flat = blockIdx.x;
    const int xcd = flat & 7;
    const int s2 = flat >> 3;                 // 0..131
    const int bh = (xcd << 2) + (s2 / 33);    // b*16 + h
    const int slot = s2 % 33;

    const int nq0 = cnts[bh];
    const int nk0 = cnts[32 + bh];
    const int c0 = (nq0 + 63) >> 6;           // q-tiles covering bucket 0

    int B, qlo, qhi;
    if (slot < c0) {
        B = 0; qlo = slot << 6; qhi = min(qlo + 64, nq0);
    } else {
        B = 1; qlo = nq0 + ((slot - c0) << 6);
        if (qlo >= SEQ) return;               // block-uniform: safe w/ barriers
        qhi = min(qlo + 64, SEQ);
    }
    const int klo = B ? (nk0 >> 6) : 0;
    const int khi = B ? (SEQ >> 6) : ((nk0 + 63) >> 6);
    const int nt = khi - klo;

    const size_t base = (size_t)bh * SEQ * DK;
    const unsigned short* Kb = Ks + base;                    // [pos][d]
    const unsigned short* Vb = Vst + (size_t)bh * DK * SEQ;  // [d][pos]

    const int srw = lane >> 3;
    const int su = lane & 7;

    // Q fragments (B-operand of swapped QK: lane fr = q-row qlo + wv*16 + fr)
    short8_t q_hi[2];
    {
        const size_t ro = base + (size_t)(qlo + wv * 16 + fr) * DK;
        q_hi[0] = *(const short8_t*)(Qs + ro + fg * 8);
        q_hi[1] = *(const short8_t*)(Qs + ro + 32 + fg * 8);
    }

    const int swz = fr & 7;
    const int u0 = ((fg ^ swz) << 3);
    const int u1 = (((4 + fg) ^ swz) << 3);
    int vuoff[4];
#pragma unroll
    for (int kg = 0; kg < 4; kg++)
        vuoff[kg] = (((kg * 2 + (fg >> 1)) ^ swz) << 3) + ((fg & 1) << 2);

    const float C2 = 0.18033688011112042f;    // 0.125 * log2(e)
    const float B2 = -14.426950408889634f;    // -10 * log2(e)

    const short4_t ones = {(short)0x3F80, (short)0x3F80, (short)0x3F80, (short)0x3F80};
    f32x4 acc_sum;
    f32x4 o_acc[4];
    const f32x4 fzero = {0.f, 0.f, 0.f, 0.f};
    acc_sum = fzero;
#pragma unroll
    for (int t = 0; t < 4; t++) o_acc[t] = fzero;

#define STAGE(T, BI)                                                          \
    {                                                                         \
        const int k0s = (T) << 6;                                             \
        _Pragma("unroll")                                                     \
        for (int i = 0; i < 2; i++) {                                         \
            const int r = wv * 16 + i * 8 + srw;                              \
            const int uo = ((su ^ (r & 7)) << 3);                             \
            __builtin_amdgcn_global_load_lds(                                 \
                (const void*)(Kb + (size_t)(k0s + r) * DK + uo),              \
                (void*)&KtL[BI][(wv * 16 + i * 8) * 64], 16, 0, 0);           \
            __builtin_amdgcn_global_load_lds(                                 \
                (const void*)(Vb + (size_t)r * SEQ + k0s + uo),               \
                (void*)&VtL[BI][(wv * 16 + i * 8) * 64], 16, 0, 0);           \
        }                                                                     \
    }

    STAGE(klo, 0);
    int cur = 0;

    for (int i = 0; i < nt; i++) {
        if (i + 1 < nt) {
            STAGE(klo + i + 1, cur ^ 1);      // 4 more loads in flight
            asm volatile("s_waitcnt vmcnt(4)" ::: "memory");  // tile i landed
        } else {
            asm volatile("s_waitcnt vmcnt(0)" ::: "memory");
        }
        __builtin_amdgcn_sched_barrier(0);
        __builtin_amdgcn_s_barrier();         // tile i visible to all waves
        __builtin_amdgcn_sched_barrier(0);

        const int k0 = (klo + i) << 6;

        // ---- V fragments into regs early (independent of S) ----
        short4_t vfr[4][4];
#pragma unroll
        for (int dt = 0; dt < 4; dt++)
#pragma unroll
            for (int kg = 0; kg < 4; kg++)
                vfr[dt][kg] = *(const short4_t*)&VtL[cur][(dt * 16 + fr) * 64 + vuoff[kg]];

        // ---- S^T = K Q^T (8 MFMA; A = K rows, B = Q) ----
        f32x4 s[4];
#pragma unroll
        for (int kg = 0; kg < 4; kg++) {
            const int rr = (kg * 16 + fr) * 64;
            short8_t kc0 = *(const short8_t*)&KtL[cur][rr + u0];
            short8_t kc1 = *(const short8_t*)&KtL[cur][rr + u1];
            f32x4 a = fzero;
            a = MFMA(kc0, q_hi[0], a);
            a = MFMA(kc1, q_hi[1], a);
            s[kg] = a;
        }

        // ---- softmax: p = exp2(s*C2 + B2); boundary tile masks by position ----
        short4_t pk[4];
        const bool mixed = B ? (k0 < nk0) : (k0 + 64 > nk0);
        if (!mixed) {
#pragma unroll
            for (int kg = 0; kg < 4; kg++) {
                union { short4_t v; unsigned short u[4]; } P;
#pragma unroll
                for (int r = 0; r < 4; r++)
                    P.u[r] = f2bf(exp2f(fmaf(s[kg][r], C2, B2)));
                pk[kg] = P.v;
            }
        } else {
#pragma unroll
            for (int kg = 0; kg < 4; kg++) {
                union { short4_t v; unsigned short u[4]; } P;
#pragma unroll
                for (int r = 0; r < 4; r++) {
                    int cb = (k0 + kg * 16 + fg * 4 + r) >= nk0;
                    float basev = (cb == B) ? B2 : -1e9f;
                    P.u[r] = f2bf(exp2f(fmaf(s[kg][r], C2, basev)));
                }
                pk[kg] = P.v;
            }
        }

        // ---- psum via MFMA: acc_sum[.][q] += sum_k P^T[k][q] ----
#pragma unroll
        for (int kg = 0; kg < 4; kg++)
            acc_sum = MFMA16(ones, pk[kg], acc_sum);

        // ---- O^T += V^T P^T (in-register A and B) ----
#pragma unroll
        for (int dt = 0; dt < 4; dt++) {
            f32x4 acc = o_acc[dt];
#pragma unroll
            for (int kg = 0; kg < 4; kg++)
                acc = MFMA16(vfr[dt][kg], pk[kg], acc);
            o_acc[dt] = acc;
        }

        __builtin_amdgcn_sched_barrier(0);
        __builtin_amdgcn_s_barrier();         // buf[cur] fully consumed
        __builtin_amdgcn_sched_barrier(0);
        cur ^= 1;
    }
#undef STAGE

    // acc_sum rows are identical; element 0 already holds the full psum for q=fr
    const float psum = acc_sum[0];

    // ---- epilogue: row q=fr scatter via qorder; cols contiguous -> float4 ----
    const int b = bh >> 4, h = bh & 15;
    const int qpos = qlo + wv * 16 + fr;
    if (qpos < qhi) {
        const int origq = qorder[(size_t)bh * SEQ + qpos];
        const float inv = 1.0f / psum;
        float* orow = out + ((size_t)(b * SEQ + origq)) * DMODEL + h * DK + fg * 4;
#pragma unroll
        for (int dt = 0; dt < 4; dt++) {
            f32x4 v = o_acc[dt];
            v *= inv;
            *(f32x4*)(orow + dt * 16) = v;
        }
    }
}

// ---------------------------------------------------------------------------

extern "C" void kernel_launch(void* const* d_in, const int* in_sizes, int n_in,
                              void* d_out, int out_size, void* d_ws, size_t ws_size,
                              hipStream_t stream)
{
    const float* query = (const float*)d_in[0];
    const float* key   = (const float*)d_in[1];
    const float* value = (const float*)d_in[2];
    const int* hash_q  = (const int*)d_in[3];
    const int* hash_k  = (const int*)d_in[4];
    const float* Wq    = (const float*)d_in[5];
    const float* bq    = (const float*)d_in[6];
    const float* Wk    = (const float*)d_in[7];
    const float* bk    = (const float*)d_in[8];
    const float* Wv    = (const float*)d_in[9];
    const float* bv    = (const float*)d_in[10];
    float* out = (float*)d_out;

    const size_t plane = (size_t)BATCH * NHEAD * SEQ * DK;   // 4,194,304 elems
    const size_t wsz = (size_t)DMODEL * DMODEL;              // 1,048,576 elems

    // Fused path needs: 4 planes + 3 X slots + 3 W slots + int arrays.
    const size_t needFused =
        (4 * plane + 3 * plane + 3 * wsz) * sizeof(unsigned short) +
        (4 * 65536 + 64) * sizeof(int);

    if (ws_size >= needFused) {
        // ---------------- 4-launch fused path ----------------
        unsigned short* ws = (unsigned short*)d_ws;
        unsigned short* pQ  = ws;
        unsigned short* pK  = ws + plane;
        unsigned short* pVt = ws + 2 * plane;                 // sorted V^T
        unsigned short* pVn = ws + 3 * plane;                 // natural V^T
        unsigned short* xq  = ws + 4 * plane;
        unsigned short* xk  = xq + plane;
        unsigned short* xv  = xk + plane;
        unsigned short* wqb = xv + plane;
        unsigned short* wkb = wqb + wsz;
        unsigned short* wvb = wkb + wsz;
        int* ip = (int*)(wvb + wsz);
        int* qorder = ip;
        int* korder = ip + 65536;
        int* qinv   = ip + 131072;
        int* kinv   = ip + 196608;
        int* cnts   = ip + 262144;

        bucket_cvt_kernel<<<64 + 7680, 256, 0, stream>>>(
            hash_q, hash_k, qorder, korder, qinv, kinv, cnts,
            query, key, value, Wq, Wk, Wv,
            xq, xk, xv, wqb, wkb, wvb);

        proj_kernel<<<1536, 256, 0, stream>>>(
            xq, xk, xv, wqb, wkb, wvb, bq, bk, bv,
            qinv, kinv, pQ, pK, pVn, 0);

        vperm_kernel<<<2048, 256, 0, stream>>>(pVn, korder, pVt);

        lsh_attn_kernel<<<dim3(1056), 256, 0, stream>>>(pQ, pK, pVt,
                                                        qorder, cnts, out);
    } else {
        // ---------------- fallback 9-launch path (r13 memory layout) --------
        unsigned short* ws = (unsigned short*)d_ws;
        unsigned short* pQ    = ws;
        unsigned short* pK    = ws + plane;
        unsigned short* pVt   = ws + 2 * plane;
        unsigned short* pVn   = ws + 3 * plane;
        unsigned short* Xslot = ws + 4 * plane;
        unsigned short* Wslot = ws + 5 * plane;
        int* ip = (int*)(ws + 5 * plane + wsz);
        int* qorder = ip;
        int* korder = ip + 65536;
        int* qinv   = ip + 131072;
        int* kinv   = ip + 196608;
        int* cnts   = ip + 262144;

        bucket_kernel<<<64, 256, 0, stream>>>(hash_q, hash_k, qorder, korder,
                                              qinv, kinv, cnts);

        const int cvtBlocks = (int)((plane + wsz) / 8 / 256);

        cvt_xw_kernel<<<cvtBlocks, 256, 0, stream>>>(query, Wq, Xslot, Wslot);
        proj_kernel<<<512, 256, 0, stream>>>(Xslot, Xslot, Xslot,
                                             Wslot, Wslot, Wslot, bq, bq, bq,
                                             qinv, qinv, pQ, pQ, pQ, 0);

        cvt_xw_kernel<<<cvtBlocks, 256, 0, stream>>>(key, Wk, Xslot, Wslot);
        proj_kernel<<<512, 256, 0, stream>>>(Xslot, Xslot, Xslot,
                                             Wslot, Wslot, Wslot, bk, bk, bk,
                                             kinv, kinv, pK, pK, pK, 1);

        cvt_xw_kernel<<<cvtBlocks, 256, 0, stream>>>(value, Wv, Xslot, Wslot);
        proj_kernel<<<512, 256, 0, stream>>>(Xslot, Xslot, Xslot,
                                             Wslot, Wslot, Wslot, bv, bv, bv,
                                             kinv, kinv, pVn, pVn, pVn, 2);

        vperm_kernel<<<2048, 256, 0, stream>>>(pVn, korder, pVt);

        lsh_attn_kernel<<<dim3(1056), 256, 0, stream>>>(pQ, pK, pVt,
                                                        qorder, cnts, out);
    }
}